// Round 4
// baseline (1670.573 us; speedup 1.0000x reference)
//
#include <hip/hip_runtime.h>
#include <hip/hip_bf16.h>

#define HD 128
#define LN_EPS 1e-5f
typedef unsigned int u32;
typedef unsigned long long u64;
typedef __attribute__((ext_vector_type(8))) short bf16x8;
typedef __attribute__((ext_vector_type(4))) float f32x4;

// ---------- bf16 pack/unpack (bit-level, round-to-nearest-even) ----------
__device__ __forceinline__ u32 f2bf(float f) {
  u32 u = __float_as_uint(f);
  return (u + 0x7FFFu + ((u >> 16) & 1u)) >> 16;
}
__device__ __forceinline__ float bf_lo(u32 p) { return __uint_as_float(p << 16); }
__device__ __forceinline__ float bf_hi(u32 p) { return __uint_as_float(p & 0xFFFF0000u); }
__device__ __forceinline__ u32 pack2(float a, float b) { return f2bf(a) | (f2bf(b) << 16); }

// ---------- block-wide (128 threads = 2 waves) dual reduction ----------
__device__ __forceinline__ void block_reduce2_128(float& a, float& b) {
  #pragma unroll
  for (int off = 32; off > 0; off >>= 1) {
    a += __shfl_down(a, off);
    b += __shfl_down(b, off);
  }
  __shared__ float pa[2], pb[2];
  int w = threadIdx.x >> 6;
  if ((threadIdx.x & 63) == 0) { pa[w] = a; pb[w] = b; }
  __syncthreads();
  a = pa[0] + pa[1];
  b = pb[0] + pb[1];
}

// ---------- CSR build ----------
__global__ void init_counts(int* __restrict__ counts, int N) {
  int i = blockIdx.x * blockDim.x + threadIdx.x;
  if (i < N) counts[i] = 0;
}

__global__ void count_deg(const int* __restrict__ dst, int* __restrict__ counts, int E) {
  int e = blockIdx.x * blockDim.x + threadIdx.x;
  if (e < E) atomicAdd(&counts[dst[e]], 1);
}

__global__ __launch_bounds__(1024) void scan1(const int* __restrict__ counts,
                                              int* __restrict__ row_ptr,
                                              int* __restrict__ bsums, int N) {
  __shared__ int s[1024];
  int t = threadIdx.x;
  int i = blockIdx.x * 1024 + t;
  int v = (i < N) ? counts[i] : 0;
  s[t] = v;
  __syncthreads();
  for (int off = 1; off < 1024; off <<= 1) {
    int u = (t >= off) ? s[t - off] : 0;
    __syncthreads();
    s[t] += u;
    __syncthreads();
  }
  if (i < N) row_ptr[i + 1] = s[t];
  if (t == 1023) bsums[blockIdx.x] = s[1023];
  if (i == 0) row_ptr[0] = 0;
}

__global__ __launch_bounds__(1024) void scan2(int* __restrict__ bsums, int nb) {
  __shared__ int s[1024];
  int t = threadIdx.x;
  int v = (t < nb) ? bsums[t] : 0;
  s[t] = v;
  __syncthreads();
  for (int off = 1; off < 1024; off <<= 1) {
    int u = (t >= off) ? s[t - off] : 0;
    __syncthreads();
    s[t] += u;
    __syncthreads();
  }
  if (t < nb) bsums[t] = (t == 0) ? 0 : s[t - 1];
}

__global__ void scan3(int* __restrict__ row_ptr, const int* __restrict__ bsums, int N) {
  int i = blockIdx.x * blockDim.x + threadIdx.x;
  if (i < N) row_ptr[i + 1] += bsums[i >> 10];
}

__global__ void copy_fill(int* __restrict__ fill, const int* __restrict__ row_ptr, int N) {
  int i = blockIdx.x * blockDim.x + threadIdx.x;
  if (i < N) fill[i] = row_ptr[i];
}

// XCD-windowed CSR scatter: class k = blockIdx%8 handles dst window k (dst>>14).
// All stores to a given col/eid line come from one XCD's L2, close in time ->
// one writeback per line instead of one per store.
__global__ void fill_col(const int* __restrict__ src, const int* __restrict__ dst,
                         int* __restrict__ fill, int* __restrict__ col,
                         int* __restrict__ eid, int E) {
  int cls = blockIdx.x & 7;
  if (cls > 6) return;                  // N=100K -> dst>>14 in [0,6]
  int nb = gridDim.x >> 3;
  int bid = blockIdx.x >> 3;
  for (int e = bid * 256 + threadIdx.x; e < E; e += nb * 256) {
    int d = dst[e];
    if ((d >> 14) == cls) {
      int pos = atomicAdd(&fill[d], 1);
      col[pos] = src[e];
      eid[pos] = e;
    }
  }
}

__global__ void compute_dinv(const int* __restrict__ counts, float* __restrict__ dinv, int N) {
  int i = blockIdx.x * blockDim.x + threadIdx.x;
  if (i < N) dinv[i] = rsqrtf((float)(counts[i] + 1));
}

// ---------- weight prep: Wtb[m][n][k] = bf16(Wsrc_m[k][n]), m=0..4 ----------
__global__ void conv_weights(const float* __restrict__ conv_w,
                             const float* __restrict__ mlp_w1,
                             u32* __restrict__ Wtb) {
  int i = blockIdx.x * 256 + threadIdx.x;
  if (i >= 5 * 128 * 64) return;
  int m = i >> 13;
  int r = i & 8191;
  int n = r >> 6;
  int k2 = r & 63;
  const float* src = (m < 3) ? conv_w + (size_t)m * HD * HD
                             : mlp_w1 + (size_t)(m - 3) * HD * HD;
  float a = src[(2 * k2) * HD + n];
  float b = src[(2 * k2 + 1) * HD + n];
  Wtb[i] = pack2(a, b);
}

// ---------- node encoder ----------
__global__ __launch_bounds__(128) void encoder(const float* __restrict__ nf,
                                               const float* __restrict__ enc_w,
                                               const float* __restrict__ enc_b,
                                               const float* __restrict__ g,
                                               const float* __restrict__ bt,
                                               float* __restrict__ x,
                                               u32* __restrict__ xb, int N) {
  int n = blockIdx.x;
  int t = threadIdx.x;
  __shared__ float f[7];
  if (t < 7) f[t] = nf[(size_t)n * 7 + t];
  __syncthreads();
  float v = enc_b[t];
  #pragma unroll
  for (int k = 0; k < 7; k++) v = fmaf(f[k], enc_w[k * HD + t], v);
  float s1 = v, s2 = v * v;
  block_reduce2_128(s1, s2);
  float mu = s1 * (1.f / HD);
  float var = s2 * (1.f / HD) - mu * mu;
  float o = fmaxf((v - mu) * rsqrtf(var + LN_EPS) * g[t] + bt[t], 0.f);
  x[(size_t)n * HD + t] = o;
  float o2 = __shfl_down(o, 1);
  if ((t & 1) == 0) xb[(size_t)n * 64 + (t >> 1)] = pack2(o, o2);
}

// ---------- MFMA GEMM: h[N,128]bf16 = xb[N,128]bf16 @ W ----------
__global__ __launch_bounds__(256) void gemm_mfma(const u32* __restrict__ xb,
                                                 const u32* __restrict__ Wt,
                                                 u32* __restrict__ h, int N) {
  __shared__ u32 lds[8192];
  int t = threadIdx.x;
  int node0 = blockIdx.x * 64;
  {
    uint4* l4 = reinterpret_cast<uint4*>(lds);
    const uint4* s4 = reinterpret_cast<const uint4*>(Wt);
    for (int i = t; i < 2048; i += 256) {
      int n = i >> 4, kc = i & 15;
      l4[(n << 4) + (kc ^ (n & 15))] = s4[i];
    }
  }
  int w = t >> 6, l = t & 63;
  int m15 = l & 15, kq = l >> 4;
  int grow = node0 + w * 16 + m15;
  bf16x8 afrag[4];
  bool rowok = grow < N;
  #pragma unroll
  for (int c = 0; c < 4; c++) {
    if (rowok)
      afrag[c] = *reinterpret_cast<const bf16x8*>(
          reinterpret_cast<const short*>(xb) + (size_t)grow * HD + c * 32 + kq * 8);
    else
      afrag[c] = bf16x8{0, 0, 0, 0, 0, 0, 0, 0};
  }
  __syncthreads();
  f32x4 acc[8];
  #pragma unroll
  for (int tl = 0; tl < 8; tl++) acc[tl] = f32x4{0.f, 0.f, 0.f, 0.f};
  const uint4* l4 = reinterpret_cast<const uint4*>(lds);
  #pragma unroll
  for (int tl = 0; tl < 8; tl++) {
    int n = tl * 16 + m15;
    #pragma unroll
    for (int c = 0; c < 4; c++) {
      bf16x8 bfrag = *reinterpret_cast<const bf16x8*>(&l4[(n << 4) + ((c * 4 + kq) ^ (n & 15))]);
      acc[tl] = __builtin_amdgcn_mfma_f32_16x16x32_bf16(afrag[c], bfrag, acc[tl], 0, 0, 0);
    }
  }
  __syncthreads();
  short* cs = reinterpret_cast<short*>(lds);
  #pragma unroll
  for (int tl = 0; tl < 8; tl++) {
    int colc = tl * 16 + m15;
    #pragma unroll
    for (int r = 0; r < 4; r++)
      cs[(w * 16 + kq * 4 + r) * 136 + colc] = (short)f2bf(acc[tl][r]);
  }
  __syncthreads();
  for (int i = t; i < 1024; i += 256) {
    int row = i >> 4;
    int node = node0 + row;
    if (node < N) {
      uint4 v = *reinterpret_cast<const uint4*>(&lds[row * 68 + (i & 15) * 4]);
      reinterpret_cast<uint4*>(h)[(size_t)node * 16 + (i & 15)] = v;
    }
  }
}

// ---------- aggregate, src-window sweep ----------
// Resident grid: 4 waves/block, 16 nodes/wave. Outer loop over 13 src-windows
// (2 MB of h each, L2-resident per XCD); per window, ballot-filter each node's
// neighbor list and gather only matching rows. Accumulators live in VGPRs
// across the whole sweep.
#define NWIN 13
#define WSH 13
__global__ __launch_bounds__(256) void aggregate(const u32* __restrict__ h,
                                                 const float* __restrict__ xin,
                                                 const int* __restrict__ rowp,
                                                 const int* __restrict__ col,
                                                 const float* __restrict__ dinv,
                                                 const float* __restrict__ conv_b,
                                                 const float* __restrict__ g,
                                                 const float* __restrict__ bt,
                                                 float* __restrict__ xout,
                                                 u32* __restrict__ xb, int N) {
  int wv = blockIdx.x * 4 + (threadIdx.x >> 6);
  int l = threadIdx.x & 63;
  int n0 = wv * 16;
  if (n0 >= N) return;
  float a0[16], a1[16];
  #pragma unroll
  for (int i = 0; i < 16; i++) {
    int n = n0 + i;
    if (n < N) {
      u32 hv = h[(size_t)n * 64 + l];     // self loop
      float dn = dinv[n];
      a0[i] = dn * bf_lo(hv);
      a1[i] = dn * bf_hi(hv);
    } else { a0[i] = 0.f; a1[i] = 0.f; }
  }
  for (int w = 0; w < NWIN; w++) {
    #pragma unroll
    for (int i = 0; i < 16; i++) {
      int n = n0 + i;
      if (n < N) {
        int beg = rowp[n], end = rowp[n + 1];
        for (int base = beg; base < end; base += 64) {
          int m = min(64, end - base);
          int s = (l < m) ? col[base + l] : -1;
          u64 mask = __ballot((s >> WSH) == w);
          while (mask) {
            int j = __builtin_ctzll(mask);
            mask &= mask - 1;
            int sj = __shfl(s, j);
            u32 v = h[(size_t)sj * 64 + l];
            float dj = dinv[sj];
            a0[i] = fmaf(dj, bf_lo(v), a0[i]);
            a1[i] = fmaf(dj, bf_hi(v), a1[i]);
          }
        }
      }
    }
  }
  #pragma unroll
  for (int i = 0; i < 16; i++) {
    int n = n0 + i;
    if (n >= N) continue;
    float dn = dinv[n];
    float2 bb = reinterpret_cast<const float2*>(conv_b)[l];
    float v0 = dn * a0[i] + bb.x;
    float v1 = dn * a1[i] + bb.y;
    float s1 = v0 + v1, s2 = v0 * v0 + v1 * v1;
    #pragma unroll
    for (int off = 32; off > 0; off >>= 1) {
      s1 += __shfl_xor(s1, off);
      s2 += __shfl_xor(s2, off);
    }
    float mu = s1 * (1.f / HD);
    float var = s2 * (1.f / HD) - mu * mu;
    float rs = rsqrtf(var + LN_EPS);
    float2 gg = reinterpret_cast<const float2*>(g)[l];
    float2 bt2 = reinterpret_cast<const float2*>(bt)[l];
    float2 xr = reinterpret_cast<const float2*>(xin)[(size_t)n * 64 + l];
    float o0 = fmaxf((v0 - mu) * rs * gg.x + bt2.x, 0.f) + xr.x;
    float o1 = fmaxf((v1 - mu) * rs * gg.y + bt2.y, 0.f) + xr.y;
    reinterpret_cast<float2*>(xout)[(size_t)n * 64 + l] = make_float2(o0, o1);
    xb[(size_t)n * 64 + l] = pack2(o0, o1);
  }
}

// ---------- edge scoring, dst-grouped; writes logits in CSR order ----------
__global__ __launch_bounds__(128) void edge_mlp(const u32* __restrict__ P,
                                                const u32* __restrict__ Q,
                                                const int* __restrict__ rowp,
                                                const int* __restrict__ col,
                                                const float* __restrict__ b1,
                                                const float* __restrict__ w2,
                                                const float* __restrict__ b2,
                                                float* __restrict__ tmp, int N) {
  int n = blockIdx.x * 2 + (threadIdx.x >> 6);
  if (n >= N) return;
  int l = threadIdx.x & 63;
  int g = l >> 4, li = l & 15;
  int beg = rowp[n], end = rowp[n + 1];
  if (beg == end) return;
  const uint4* P4 = reinterpret_cast<const uint4*>(P);
  uint4 qv = reinterpret_cast<const uint4*>(Q)[(size_t)n * 16 + li];
  float4 bA = reinterpret_cast<const float4*>(b1)[2 * li];
  float4 bB = reinterpret_cast<const float4*>(b1)[2 * li + 1];
  float4 wA = reinterpret_cast<const float4*>(w2)[2 * li];
  float4 wB = reinterpret_cast<const float4*>(w2)[2 * li + 1];
  float q0 = bf_lo(qv.x) + bA.x, q1 = bf_hi(qv.x) + bA.y;
  float q2 = bf_lo(qv.y) + bA.z, q3 = bf_hi(qv.y) + bA.w;
  float q4 = bf_lo(qv.z) + bB.x, q5 = bf_hi(qv.z) + bB.y;
  float q6 = bf_lo(qv.w) + bB.z, q7 = bf_hi(qv.w) + bB.w;
  float b2v = b2[0];
  for (int base = beg; base < end; base += 64) {
    int m = min(64, end - base);
    int s = 0;
    if (l < m) s = col[base + l];
    int nj = (m + 3) >> 2;
    for (int j = 0; j < nj; j++) {
      int ei = j * 4 + g;
      int sj = __shfl(s, ei);
      float acc = 0.f;
      if (ei < m) {
        uint4 pv = P4[(size_t)sj * 16 + li];
        float hh;
        hh = fmaxf(bf_lo(pv.x) + q0, 0.f); acc = fmaf(hh, wA.x, acc);
        hh = fmaxf(bf_hi(pv.x) + q1, 0.f); acc = fmaf(hh, wA.y, acc);
        hh = fmaxf(bf_lo(pv.y) + q2, 0.f); acc = fmaf(hh, wA.z, acc);
        hh = fmaxf(bf_hi(pv.y) + q3, 0.f); acc = fmaf(hh, wA.w, acc);
        hh = fmaxf(bf_lo(pv.z) + q4, 0.f); acc = fmaf(hh, wB.x, acc);
        hh = fmaxf(bf_hi(pv.z) + q5, 0.f); acc = fmaf(hh, wB.y, acc);
        hh = fmaxf(bf_lo(pv.w) + q6, 0.f); acc = fmaf(hh, wB.z, acc);
        hh = fmaxf(bf_hi(pv.w) + q7, 0.f); acc = fmaf(hh, wB.w, acc);
      }
      acc += __shfl_down(acc, 8, 16);
      acc += __shfl_down(acc, 4, 16);
      acc += __shfl_down(acc, 2, 16);
      acc += __shfl_down(acc, 1, 16);
      if (li == 0 && ei < m) tmp[base + ei] = acc + b2v;
    }
  }
}

// ---------- windowed permute-scatter: out[eid[i]] = tmp[i] ----------
// class k handles e-window k (e>>18): out-line stores stay XCD-local.
__global__ void permute_scatter(const float* __restrict__ tmp, const int* __restrict__ eid,
                                float* __restrict__ out, int E) {
  int cls = blockIdx.x & 7;
  if (cls > 6) return;                  // E=1.6M -> e>>18 in [0,6]
  int nb = gridDim.x >> 3;
  int bid = blockIdx.x >> 3;
  for (int i = bid * 256 + threadIdx.x; i < E; i += nb * 256) {
    int e = eid[i];
    if ((e >> 18) == cls) out[e] = tmp[i];
  }
}

extern "C" void kernel_launch(void* const* d_in, const int* in_sizes, int n_in,
                              void* d_out, int out_size, void* d_ws, size_t ws_size,
                              hipStream_t stream) {
  const float* node_features = (const float*)d_in[0];
  const int*   edge_index    = (const int*)d_in[1];
  const float* enc_w    = (const float*)d_in[3];
  const float* enc_b    = (const float*)d_in[4];
  const float* enc_ln_g = (const float*)d_in[5];
  const float* enc_ln_b = (const float*)d_in[6];
  const float* conv_w   = (const float*)d_in[7];
  const float* conv_b   = (const float*)d_in[8];
  const float* ln_g     = (const float*)d_in[9];
  const float* ln_b     = (const float*)d_in[10];
  const float* mlp_w1   = (const float*)d_in[11];
  const float* mlp_b1   = (const float*)d_in[12];
  const float* mlp_w2   = (const float*)d_in[13];
  const float* mlp_b2   = (const float*)d_in[14];

  const int N = in_sizes[0] / 7;
  const int E = in_sizes[1] / 2;
  const int* src = edge_index;
  const int* dst = edge_index + E;

  char* ws = (char*)d_ws;
  float* x    = (float*)ws;  ws += (size_t)N * HD * 4;
  u32*   h    = (u32*)ws;    ws += (size_t)N * 64 * 4;
  u32*   qb   = (u32*)ws;    ws += (size_t)N * 64 * 4;
  u32*   xb   = (u32*)ws;    ws += (size_t)N * 64 * 4;
  u32*   Wtb  = (u32*)ws;    ws += (size_t)5 * 128 * 64 * 4;
  float* dinv = (float*)ws;  ws += (size_t)N * 4;
  int* counts = (int*)ws;    ws += (size_t)N * 4;
  int* fill   = (int*)ws;    ws += (size_t)N * 4;
  int* col    = (int*)ws;    ws += (size_t)E * 4;
  int* eid    = (int*)ws;    ws += (size_t)E * 4;
  int* rowp   = (int*)ws;    ws += (size_t)(N + 1) * 4;
  int* bsums  = (int*)ws;    ws += 4096;
  float* tmp  = x;                       // alias: x dead when edge_mlp runs

  float* out_x      = (float*)d_out;
  float* out_logits = out_x + (size_t)N * HD;

  const int T = 256;
  int nblk = (N + 1023) / 1024;

  init_counts<<<(N + T - 1) / T, T, 0, stream>>>(counts, N);
  count_deg<<<(E + T - 1) / T, T, 0, stream>>>(dst, counts, E);
  scan1<<<nblk, 1024, 0, stream>>>(counts, rowp, bsums, N);
  scan2<<<1, 1024, 0, stream>>>(bsums, nblk);
  scan3<<<(N + T - 1) / T, T, 0, stream>>>(rowp, bsums, N);
  copy_fill<<<(N + T - 1) / T, T, 0, stream>>>(fill, rowp, N);
  fill_col<<<3584, 256, 0, stream>>>(src, dst, fill, col, eid, E);
  compute_dinv<<<(N + T - 1) / T, T, 0, stream>>>(counts, dinv, N);

  conv_weights<<<(5 * 128 * 64 + T - 1) / T, T, 0, stream>>>(conv_w, mlp_w1, Wtb);

  encoder<<<N, 128, 0, stream>>>(node_features, enc_w, enc_b, enc_ln_g, enc_ln_b, x, xb, N);

  int gblk = (N + 63) / 64;
  int ablk = (N + 63) / 64;   // 4 waves/block x 16 nodes/wave
  for (int l = 0; l < 3; l++) {
    gemm_mfma<<<gblk, 256, 0, stream>>>(xb, Wtb + (size_t)l * 8192, h, N);
    float* xout = (l == 2) ? out_x : x;
    aggregate<<<ablk, 256, 0, stream>>>(h, x, rowp, col, dinv,
                                        conv_b + l * HD, ln_g + l * HD, ln_b + l * HD,
                                        xout, xb, N);
  }

  gemm_mfma<<<gblk, 256, 0, stream>>>(xb, Wtb + (size_t)3 * 8192, h, N);   // P
  gemm_mfma<<<gblk, 256, 0, stream>>>(xb, Wtb + (size_t)4 * 8192, qb, N);  // Q
  edge_mlp<<<(N + 1) / 2, 128, 0, stream>>>(h, qb, rowp, col, mlp_b1, mlp_w2, mlp_b2, tmp, N);
  permute_scatter<<<3584, 256, 0, stream>>>(tmp, eid, out_logits, E);
}

// Round 5
// 687.238 us; speedup vs baseline: 2.4309x; 2.4309x over previous
//
#include <hip/hip_runtime.h>
#include <hip/hip_bf16.h>

#define HD 128
#define LN_EPS 1e-5f
typedef unsigned int u32;
typedef unsigned long long u64;
typedef __attribute__((ext_vector_type(8))) short bf16x8;
typedef __attribute__((ext_vector_type(4))) float f32x4;

// ---------- bf16 pack/unpack (bit-level, round-to-nearest-even) ----------
__device__ __forceinline__ u32 f2bf(float f) {
  u32 u = __float_as_uint(f);
  return (u + 0x7FFFu + ((u >> 16) & 1u)) >> 16;
}
__device__ __forceinline__ float bf_lo(u32 p) { return __uint_as_float(p << 16); }
__device__ __forceinline__ float bf_hi(u32 p) { return __uint_as_float(p & 0xFFFF0000u); }
__device__ __forceinline__ u32 pack2(float a, float b) { return f2bf(a) | (f2bf(b) << 16); }

// ---------- block-wide (128 threads = 2 waves) dual reduction ----------
__device__ __forceinline__ void block_reduce2_128(float& a, float& b) {
  #pragma unroll
  for (int off = 32; off > 0; off >>= 1) {
    a += __shfl_down(a, off);
    b += __shfl_down(b, off);
  }
  __shared__ float pa[2], pb[2];
  int w = threadIdx.x >> 6;
  if ((threadIdx.x & 63) == 0) { pa[w] = a; pb[w] = b; }
  __syncthreads();
  a = pa[0] + pa[1];
  b = pb[0] + pb[1];
}

// ---------- CSR build ----------
__global__ void init_counts(int* __restrict__ counts, int N) {
  int i = blockIdx.x * blockDim.x + threadIdx.x;
  if (i < N) counts[i] = 0;
}

__global__ void count_deg(const int* __restrict__ dst, int* __restrict__ counts, int E) {
  int e = blockIdx.x * blockDim.x + threadIdx.x;
  if (e < E) atomicAdd(&counts[dst[e]], 1);
}

__global__ __launch_bounds__(1024) void scan1(const int* __restrict__ counts,
                                              int* __restrict__ row_ptr,
                                              int* __restrict__ bsums, int N) {
  __shared__ int s[1024];
  int t = threadIdx.x;
  int i = blockIdx.x * 1024 + t;
  int v = (i < N) ? counts[i] : 0;
  s[t] = v;
  __syncthreads();
  for (int off = 1; off < 1024; off <<= 1) {
    int u = (t >= off) ? s[t - off] : 0;
    __syncthreads();
    s[t] += u;
    __syncthreads();
  }
  if (i < N) row_ptr[i + 1] = s[t];
  if (t == 1023) bsums[blockIdx.x] = s[1023];
  if (i == 0) row_ptr[0] = 0;
}

__global__ __launch_bounds__(1024) void scan2(int* __restrict__ bsums, int nb) {
  __shared__ int s[1024];
  int t = threadIdx.x;
  int v = (t < nb) ? bsums[t] : 0;
  s[t] = v;
  __syncthreads();
  for (int off = 1; off < 1024; off <<= 1) {
    int u = (t >= off) ? s[t - off] : 0;
    __syncthreads();
    s[t] += u;
    __syncthreads();
  }
  if (t < nb) bsums[t] = (t == 0) ? 0 : s[t - 1];
}

__global__ void scan3(int* __restrict__ row_ptr, const int* __restrict__ bsums, int N) {
  int i = blockIdx.x * blockDim.x + threadIdx.x;
  if (i < N) row_ptr[i + 1] += bsums[i >> 10];
}

__global__ void copy_fill(int* __restrict__ fill, const int* __restrict__ row_ptr, int N) {
  int i = blockIdx.x * blockDim.x + threadIdx.x;
  if (i < N) fill[i] = row_ptr[i];
}

// XCD-windowed CSR scatter: class k = blockIdx%8 handles dst window k (dst>>14).
__global__ void fill_col(const int* __restrict__ src, const int* __restrict__ dst,
                         int* __restrict__ fill, int* __restrict__ col,
                         int* __restrict__ eid, int E) {
  int cls = blockIdx.x & 7;
  if (cls > 6) return;                  // N=100K -> dst>>14 in [0,6]
  int nb = gridDim.x >> 3;
  int bid = blockIdx.x >> 3;
  for (int e = bid * 256 + threadIdx.x; e < E; e += nb * 256) {
    int d = dst[e];
    if ((d >> 14) == cls) {
      int pos = atomicAdd(&fill[d], 1);
      col[pos] = src[e];
      eid[pos] = e;
    }
  }
}

__global__ void compute_dinv(const int* __restrict__ counts, float* __restrict__ dinv, int N) {
  int i = blockIdx.x * blockDim.x + threadIdx.x;
  if (i < N) dinv[i] = rsqrtf((float)(counts[i] + 1));
}

// ---------- weight prep: Wtb[m][n][k] = bf16(Wsrc_m[k][n]), m=0..4 ----------
__global__ void conv_weights(const float* __restrict__ conv_w,
                             const float* __restrict__ mlp_w1,
                             u32* __restrict__ Wtb) {
  int i = blockIdx.x * 256 + threadIdx.x;
  if (i >= 5 * 128 * 64) return;
  int m = i >> 13;
  int r = i & 8191;
  int n = r >> 6;
  int k2 = r & 63;
  const float* src = (m < 3) ? conv_w + (size_t)m * HD * HD
                             : mlp_w1 + (size_t)(m - 3) * HD * HD;
  float a = src[(2 * k2) * HD + n];
  float b = src[(2 * k2 + 1) * HD + n];
  Wtb[i] = pack2(a, b);
}

// ---------- node encoder: Linear(7->128) + LN + ReLU -> bf16 xb only ----------
__global__ __launch_bounds__(128) void encoder(const float* __restrict__ nf,
                                               const float* __restrict__ enc_w,
                                               const float* __restrict__ enc_b,
                                               const float* __restrict__ g,
                                               const float* __restrict__ bt,
                                               u32* __restrict__ xb, int N) {
  int n = blockIdx.x;
  int t = threadIdx.x;
  __shared__ float f[7];
  if (t < 7) f[t] = nf[(size_t)n * 7 + t];
  __syncthreads();
  float v = enc_b[t];
  #pragma unroll
  for (int k = 0; k < 7; k++) v = fmaf(f[k], enc_w[k * HD + t], v);
  float s1 = v, s2 = v * v;
  block_reduce2_128(s1, s2);
  float mu = s1 * (1.f / HD);
  float var = s2 * (1.f / HD) - mu * mu;
  float o = fmaxf((v - mu) * rsqrtf(var + LN_EPS) * g[t] + bt[t], 0.f);
  float o2 = __shfl_down(o, 1);
  if ((t & 1) == 0) xb[(size_t)n * 64 + (t >> 1)] = pack2(o, o2);
}

// ---------- MFMA GEMM: h[N,128]bf16 = xb[N,128]bf16 @ W ----------
__global__ __launch_bounds__(256) void gemm_mfma(const u32* __restrict__ xb,
                                                 const u32* __restrict__ Wt,
                                                 u32* __restrict__ h, int N) {
  __shared__ u32 lds[8192];
  int t = threadIdx.x;
  int node0 = blockIdx.x * 64;
  {
    uint4* l4 = reinterpret_cast<uint4*>(lds);
    const uint4* s4 = reinterpret_cast<const uint4*>(Wt);
    for (int i = t; i < 2048; i += 256) {
      int n = i >> 4, kc = i & 15;
      l4[(n << 4) + (kc ^ (n & 15))] = s4[i];
    }
  }
  int w = t >> 6, l = t & 63;
  int m15 = l & 15, kq = l >> 4;
  int grow = node0 + w * 16 + m15;
  bf16x8 afrag[4];
  bool rowok = grow < N;
  #pragma unroll
  for (int c = 0; c < 4; c++) {
    if (rowok)
      afrag[c] = *reinterpret_cast<const bf16x8*>(
          reinterpret_cast<const short*>(xb) + (size_t)grow * HD + c * 32 + kq * 8);
    else
      afrag[c] = bf16x8{0, 0, 0, 0, 0, 0, 0, 0};
  }
  __syncthreads();
  f32x4 acc[8];
  #pragma unroll
  for (int tl = 0; tl < 8; tl++) acc[tl] = f32x4{0.f, 0.f, 0.f, 0.f};
  const uint4* l4 = reinterpret_cast<const uint4*>(lds);
  #pragma unroll
  for (int tl = 0; tl < 8; tl++) {
    int n = tl * 16 + m15;
    #pragma unroll
    for (int c = 0; c < 4; c++) {
      bf16x8 bfrag = *reinterpret_cast<const bf16x8*>(&l4[(n << 4) + ((c * 4 + kq) ^ (n & 15))]);
      acc[tl] = __builtin_amdgcn_mfma_f32_16x16x32_bf16(afrag[c], bfrag, acc[tl], 0, 0, 0);
    }
  }
  __syncthreads();
  short* cs = reinterpret_cast<short*>(lds);
  #pragma unroll
  for (int tl = 0; tl < 8; tl++) {
    int colc = tl * 16 + m15;
    #pragma unroll
    for (int r = 0; r < 4; r++)
      cs[(w * 16 + kq * 4 + r) * 136 + colc] = (short)f2bf(acc[tl][r]);
  }
  __syncthreads();
  for (int i = t; i < 1024; i += 256) {
    int row = i >> 4;
    int node = node0 + row;
    if (node < N) {
      uint4 v = *reinterpret_cast<const uint4*>(&lds[row * 68 + (i & 15) * 4]);
      reinterpret_cast<uint4*>(h)[(size_t)node * 16 + (i & 15)] = v;
    }
  }
}

// ---------- fused gather-aggregate + bias + LN + ReLU + residual ----------
// wave per node; lane l owns channels 2l,2l+1. Node state xb (bf16) updated
// in place (each row touched only by its own wave). Last layer also writes
// fp32 out_x.
__global__ __launch_bounds__(256) void aggregate(const u32* __restrict__ h,
                                                 const int* __restrict__ row_ptr,
                                                 const int* __restrict__ col,
                                                 const float* __restrict__ dinv,
                                                 const float* __restrict__ conv_b,
                                                 const float* __restrict__ g,
                                                 const float* __restrict__ bt,
                                                 u32* __restrict__ xb,
                                                 float* __restrict__ out_x,
                                                 int N, int last) {
  int n = blockIdx.x * 4 + (threadIdx.x >> 6);
  if (n >= N) return;
  int l = threadIdx.x & 63;
  int beg = row_ptr[n], end = row_ptr[n + 1];
  float dn = dinv[n];
  u32 hv = h[(size_t)n * 64 + l];          // self loop
  float a0 = dn * bf_lo(hv), a1 = dn * bf_hi(hv);
  for (int base = beg; base < end; base += 64) {
    int m = min(64, end - base);
    int s = 0; float dv = 0.f;
    if (l < m) { s = col[base + l]; dv = dinv[s]; }
    int j = 0;
    for (; j + 8 <= m; j += 8) {
      int ss[8]; float dd[8]; u32 vv[8];
      #pragma unroll
      for (int q = 0; q < 8; q++) { ss[q] = __shfl(s, j + q); dd[q] = __shfl(dv, j + q); }
      #pragma unroll
      for (int q = 0; q < 8; q++) vv[q] = h[(size_t)ss[q] * 64 + l];
      #pragma unroll
      for (int q = 0; q < 8; q++) {
        a0 = fmaf(dd[q], bf_lo(vv[q]), a0);
        a1 = fmaf(dd[q], bf_hi(vv[q]), a1);
      }
    }
    for (; j < m; j++) {
      int sj = __shfl(s, j);
      float dj = __shfl(dv, j);
      u32 v = h[(size_t)sj * 64 + l];
      a0 = fmaf(dj, bf_lo(v), a0); a1 = fmaf(dj, bf_hi(v), a1);
    }
  }
  float2 bb = reinterpret_cast<const float2*>(conv_b)[l];
  float v0 = dn * a0 + bb.x;
  float v1 = dn * a1 + bb.y;
  float s1 = v0 + v1, s2 = v0 * v0 + v1 * v1;
  #pragma unroll
  for (int off = 32; off > 0; off >>= 1) {
    s1 += __shfl_xor(s1, off);
    s2 += __shfl_xor(s2, off);
  }
  float mu = s1 * (1.f / HD);
  float var = s2 * (1.f / HD) - mu * mu;
  float rs = rsqrtf(var + LN_EPS);
  float2 gg = reinterpret_cast<const float2*>(g)[l];
  float2 bt2 = reinterpret_cast<const float2*>(bt)[l];
  u32 xv = xb[(size_t)n * 64 + l];
  float o0 = fmaxf((v0 - mu) * rs * gg.x + bt2.x, 0.f) + bf_lo(xv);
  float o1 = fmaxf((v1 - mu) * rs * gg.y + bt2.y, 0.f) + bf_hi(xv);
  xb[(size_t)n * 64 + l] = pack2(o0, o1);
  if (last) reinterpret_cast<float2*>(out_x)[(size_t)n * 64 + l] = make_float2(o0, o1);
}

// ---------- edge scoring, dst-grouped; writes logits in CSR order ----------
__global__ __launch_bounds__(128) void edge_mlp(const u32* __restrict__ P,
                                                const u32* __restrict__ Q,
                                                const int* __restrict__ rowp,
                                                const int* __restrict__ col,
                                                const float* __restrict__ b1,
                                                const float* __restrict__ w2,
                                                const float* __restrict__ b2,
                                                float* __restrict__ tmp, int N) {
  int n = blockIdx.x * 2 + (threadIdx.x >> 6);
  if (n >= N) return;
  int l = threadIdx.x & 63;
  int g = l >> 4, li = l & 15;
  int beg = rowp[n], end = rowp[n + 1];
  if (beg == end) return;
  const uint4* P4 = reinterpret_cast<const uint4*>(P);
  uint4 qv = reinterpret_cast<const uint4*>(Q)[(size_t)n * 16 + li];
  float4 bA = reinterpret_cast<const float4*>(b1)[2 * li];
  float4 bB = reinterpret_cast<const float4*>(b1)[2 * li + 1];
  float4 wA = reinterpret_cast<const float4*>(w2)[2 * li];
  float4 wB = reinterpret_cast<const float4*>(w2)[2 * li + 1];
  float q0 = bf_lo(qv.x) + bA.x, q1 = bf_hi(qv.x) + bA.y;
  float q2 = bf_lo(qv.y) + bA.z, q3 = bf_hi(qv.y) + bA.w;
  float q4 = bf_lo(qv.z) + bB.x, q5 = bf_hi(qv.z) + bB.y;
  float q6 = bf_lo(qv.w) + bB.z, q7 = bf_hi(qv.w) + bB.w;
  float b2v = b2[0];
  for (int base = beg; base < end; base += 64) {
    int m = min(64, end - base);
    int s = 0;
    if (l < m) s = col[base + l];
    int nj = (m + 3) >> 2;
    for (int j = 0; j < nj; j++) {
      int ei = j * 4 + g;
      int sj = __shfl(s, ei);
      float acc = 0.f;
      if (ei < m) {
        uint4 pv = P4[(size_t)sj * 16 + li];
        float hh;
        hh = fmaxf(bf_lo(pv.x) + q0, 0.f); acc = fmaf(hh, wA.x, acc);
        hh = fmaxf(bf_hi(pv.x) + q1, 0.f); acc = fmaf(hh, wA.y, acc);
        hh = fmaxf(bf_lo(pv.y) + q2, 0.f); acc = fmaf(hh, wA.z, acc);
        hh = fmaxf(bf_hi(pv.y) + q3, 0.f); acc = fmaf(hh, wA.w, acc);
        hh = fmaxf(bf_lo(pv.z) + q4, 0.f); acc = fmaf(hh, wB.x, acc);
        hh = fmaxf(bf_hi(pv.z) + q5, 0.f); acc = fmaf(hh, wB.y, acc);
        hh = fmaxf(bf_lo(pv.w) + q6, 0.f); acc = fmaf(hh, wB.z, acc);
        hh = fmaxf(bf_hi(pv.w) + q7, 0.f); acc = fmaf(hh, wB.w, acc);
      }
      acc += __shfl_down(acc, 8, 16);
      acc += __shfl_down(acc, 4, 16);
      acc += __shfl_down(acc, 2, 16);
      acc += __shfl_down(acc, 1, 16);
      if (li == 0 && ei < m) tmp[base + ei] = acc + b2v;
    }
  }
}

// ---------- windowed permute-scatter: out[eid[i]] = tmp[i] ----------
__global__ void permute_scatter(const float* __restrict__ tmp, const int* __restrict__ eid,
                                float* __restrict__ out, int E) {
  int cls = blockIdx.x & 7;
  if (cls > 6) return;                  // E=1.6M -> e>>18 in [0,6]
  int nb = gridDim.x >> 3;
  int bid = blockIdx.x >> 3;
  for (int i = bid * 256 + threadIdx.x; i < E; i += nb * 256) {
    int e = eid[i];
    if ((e >> 18) == cls) out[e] = tmp[i];
  }
}

extern "C" void kernel_launch(void* const* d_in, const int* in_sizes, int n_in,
                              void* d_out, int out_size, void* d_ws, size_t ws_size,
                              hipStream_t stream) {
  const float* node_features = (const float*)d_in[0];
  const int*   edge_index    = (const int*)d_in[1];
  const float* enc_w    = (const float*)d_in[3];
  const float* enc_b    = (const float*)d_in[4];
  const float* enc_ln_g = (const float*)d_in[5];
  const float* enc_ln_b = (const float*)d_in[6];
  const float* conv_w   = (const float*)d_in[7];
  const float* conv_b   = (const float*)d_in[8];
  const float* ln_g     = (const float*)d_in[9];
  const float* ln_b     = (const float*)d_in[10];
  const float* mlp_w1   = (const float*)d_in[11];
  const float* mlp_b1   = (const float*)d_in[12];
  const float* mlp_w2   = (const float*)d_in[13];
  const float* mlp_b2   = (const float*)d_in[14];

  const int N = in_sizes[0] / 7;
  const int E = in_sizes[1] / 2;
  const int* src = edge_index;
  const int* dst = edge_index + E;

  char* ws = (char*)d_ws;
  u32*   h    = (u32*)ws;    ws += (size_t)N * 64 * 4;
  u32*   qb   = (u32*)ws;    ws += (size_t)N * 64 * 4;
  u32*   xb   = (u32*)ws;    ws += (size_t)N * 64 * 4;
  u32*   Wtb  = (u32*)ws;    ws += (size_t)5 * 128 * 64 * 4;
  float* dinv = (float*)ws;  ws += (size_t)N * 4;
  int* counts = (int*)ws;    ws += (size_t)N * 4;
  int* fill   = (int*)ws;    ws += (size_t)N * 4;
  int* col    = (int*)ws;    ws += (size_t)E * 4;
  int* eid    = (int*)ws;    ws += (size_t)E * 4;
  int* rowp   = (int*)ws;    ws += (size_t)(N + 1) * 4;
  int* bsums  = (int*)ws;    ws += 4096;
  float* tmp  = (float*)ws;  ws += (size_t)E * 4;

  float* out_x      = (float*)d_out;
  float* out_logits = out_x + (size_t)N * HD;

  const int T = 256;
  int nblk = (N + 1023) / 1024;

  init_counts<<<(N + T - 1) / T, T, 0, stream>>>(counts, N);
  count_deg<<<(E + T - 1) / T, T, 0, stream>>>(dst, counts, E);
  scan1<<<nblk, 1024, 0, stream>>>(counts, rowp, bsums, N);
  scan2<<<1, 1024, 0, stream>>>(bsums, nblk);
  scan3<<<(N + T - 1) / T, T, 0, stream>>>(rowp, bsums, N);
  copy_fill<<<(N + T - 1) / T, T, 0, stream>>>(fill, rowp, N);
  fill_col<<<3584, 256, 0, stream>>>(src, dst, fill, col, eid, E);
  compute_dinv<<<(N + T - 1) / T, T, 0, stream>>>(counts, dinv, N);

  conv_weights<<<(5 * 128 * 64 + T - 1) / T, T, 0, stream>>>(conv_w, mlp_w1, Wtb);

  encoder<<<N, 128, 0, stream>>>(node_features, enc_w, enc_b, enc_ln_g, enc_ln_b, xb, N);

  int gblk = (N + 63) / 64;
  int ablk = (N + 3) / 4;
  for (int l = 0; l < 3; l++) {
    gemm_mfma<<<gblk, 256, 0, stream>>>(xb, Wtb + (size_t)l * 8192, h, N);
    aggregate<<<ablk, 256, 0, stream>>>(h, rowp, col, dinv,
                                        conv_b + l * HD, ln_g + l * HD, ln_b + l * HD,
                                        xb, out_x, N, l == 2 ? 1 : 0);
  }

  gemm_mfma<<<gblk, 256, 0, stream>>>(xb, Wtb + (size_t)3 * 8192, h, N);   // P
  gemm_mfma<<<gblk, 256, 0, stream>>>(xb, Wtb + (size_t)4 * 8192, qb, N);  // Q
  edge_mlp<<<(N + 1) / 2, 128, 0, stream>>>(h, qb, rowp, col, mlp_b1, mlp_w2, mlp_b2, tmp, N);
  permute_scatter<<<3584, 256, 0, stream>>>(tmp, eid, out_logits, E);
}

// Round 6
// 678.686 us; speedup vs baseline: 2.4615x; 1.0126x over previous
//
#include <hip/hip_runtime.h>
#include <hip/hip_bf16.h>

#define HD 128
#define LN_EPS 1e-5f
typedef unsigned int u32;
typedef unsigned long long u64;
typedef __attribute__((ext_vector_type(8))) short bf16x8;
typedef __attribute__((ext_vector_type(4))) float f32x4;

// ---------- bf16 pack/unpack (bit-level, round-to-nearest-even) ----------
__device__ __forceinline__ u32 f2bf(float f) {
  u32 u = __float_as_uint(f);
  return (u + 0x7FFFu + ((u >> 16) & 1u)) >> 16;
}
__device__ __forceinline__ float bf_lo(u32 p) { return __uint_as_float(p << 16); }
__device__ __forceinline__ float bf_hi(u32 p) { return __uint_as_float(p & 0xFFFF0000u); }
__device__ __forceinline__ u32 pack2(float a, float b) { return f2bf(a) | (f2bf(b) << 16); }

// ---------- block-wide (128 threads = 2 waves) dual reduction ----------
__device__ __forceinline__ void block_reduce2_128(float& a, float& b) {
  #pragma unroll
  for (int off = 32; off > 0; off >>= 1) {
    a += __shfl_down(a, off);
    b += __shfl_down(b, off);
  }
  __shared__ float pa[2], pb[2];
  int w = threadIdx.x >> 6;
  if ((threadIdx.x & 63) == 0) { pa[w] = a; pb[w] = b; }
  __syncthreads();
  a = pa[0] + pa[1];
  b = pb[0] + pb[1];
}

// ---------- CSR build: degree + scan ----------
__global__ void init_counts(int* __restrict__ counts, int N) {
  int i = blockIdx.x * blockDim.x + threadIdx.x;
  if (i < N) counts[i] = 0;
}

__global__ void count_deg(const int* __restrict__ dst, int* __restrict__ counts, int E) {
  int e = blockIdx.x * blockDim.x + threadIdx.x;
  if (e < E) atomicAdd(&counts[dst[e]], 1);
}

__global__ __launch_bounds__(1024) void scan1(const int* __restrict__ counts,
                                              int* __restrict__ row_ptr,
                                              int* __restrict__ bsums, int N) {
  __shared__ int s[1024];
  int t = threadIdx.x;
  int i = blockIdx.x * 1024 + t;
  int v = (i < N) ? counts[i] : 0;
  s[t] = v;
  __syncthreads();
  for (int off = 1; off < 1024; off <<= 1) {
    int u = (t >= off) ? s[t - off] : 0;
    __syncthreads();
    s[t] += u;
    __syncthreads();
  }
  if (i < N) row_ptr[i + 1] = s[t];
  if (t == 1023) bsums[blockIdx.x] = s[1023];
  if (i == 0) row_ptr[0] = 0;
}

__global__ __launch_bounds__(1024) void scan2(int* __restrict__ bsums, int nb) {
  __shared__ int s[1024];
  int t = threadIdx.x;
  int v = (t < nb) ? bsums[t] : 0;
  s[t] = v;
  __syncthreads();
  for (int off = 1; off < 1024; off <<= 1) {
    int u = (t >= off) ? s[t - off] : 0;
    __syncthreads();
    s[t] += u;
    __syncthreads();
  }
  if (t < nb) bsums[t] = (t == 0) ? 0 : s[t - 1];
}

__global__ void scan3(int* __restrict__ row_ptr, const int* __restrict__ bsums, int N) {
  int i = blockIdx.x * blockDim.x + threadIdx.x;
  if (i < N) row_ptr[i + 1] += bsums[i >> 10];
}

__global__ void compute_dinv(const int* __restrict__ counts, float* __restrict__ dinv, int N) {
  int i = blockIdx.x * blockDim.x + threadIdx.x;
  if (i < N) dinv[i] = rsqrtf((float)(counts[i] + 1));
}

// ---------- CSR build pass 1: LDS-binned bucket scatter (coalesced runs) ----------
// Buckets of 512 dst nodes (id = dst>>9). Staging regions are the CSR layout
// itself (bucket base = rowp[b*512]); within-bucket order arbitrary.
// pk = e | (dst_low9 << 21)   (e < 2^21, 9-bit local dst)
__global__ __launch_bounds__(256) void binscat(const int* __restrict__ src,
                                               const int* __restrict__ dst,
                                               int* __restrict__ bfill,
                                               u32* __restrict__ src_stage,
                                               u32* __restrict__ pk_stage,
                                               int E, int nbk) {
  __shared__ int cnt[256];
  __shared__ int ofs[256];
  __shared__ int cur[256];
  __shared__ int gbase[256];
  __shared__ u32 s_src[8192];            // 32 KB
  __shared__ u32 s_pk[8192];             // 32 KB
  __shared__ unsigned char s_bk[8192];   // 8 KB
  int t = threadIdx.x;
  int base = blockIdx.x * 8192;
  int total = min(8192, E - base);
  if (total <= 0) return;
  for (int i = t; i < nbk; i += 256) cnt[i] = 0;
  __syncthreads();
  // phase A: count buckets in this chunk
  for (int i = 0; i < 32; i++) {
    int idx = base + i * 256 + t;
    if (idx < E) atomicAdd(&cnt[dst[idx] >> 9], 1);
  }
  __syncthreads();
  if (t == 0) {                          // serial scan over <=256 buckets
    int run = 0;
    for (int b = 0; b < nbk; b++) { ofs[b] = run; run += cnt[b]; }
  }
  __syncthreads();
  for (int i = t; i < nbk; i += 256) cur[i] = ofs[i];
  __syncthreads();
  // phase B: place edges into LDS, bucket-contiguous (re-read is L2-hot)
  for (int i = 0; i < 32; i++) {
    int idx = base + i * 256 + t;
    if (idx < E) {
      int d = dst[idx];
      int b = d >> 9;
      int slot = atomicAdd(&cur[b], 1);
      s_src[slot] = (u32)src[idx];
      s_pk[slot] = (u32)idx | ((u32)(d & 511) << 21);
      s_bk[slot] = (unsigned char)b;
    }
  }
  __syncthreads();
  // phase C: reserve global runs, copy LDS->global coalesced
  for (int i = t; i < nbk; i += 256)
    if (cnt[i] > 0) gbase[i] = atomicAdd(&bfill[i], cnt[i]);
  __syncthreads();
  for (int i = t; i < total; i += 256) {
    int b = s_bk[i];
    int g = gbase[b] + (i - ofs[b]);
    src_stage[g] = s_src[i];
    pk_stage[g] = s_pk[i];
  }
}

__global__ void init_bfill(const int* __restrict__ rowp, int* __restrict__ bfill, int nbk) {
  int b = blockIdx.x * blockDim.x + threadIdx.x;
  if (b < nbk) bfill[b] = rowp[b << 9];
}

// ---------- CSR build pass 2: per-bucket fine scatter, LDS fill counters ----------
// One block per bucket; col/eid region (~65 KB) written by a single CU ->
// lines accumulate in its L2, writeback ~= payload. No global atomics.
__global__ __launch_bounds__(256) void bucket_build(const u32* __restrict__ src_stage,
                                                    const u32* __restrict__ pk_stage,
                                                    const int* __restrict__ rowp,
                                                    int* __restrict__ col,
                                                    int* __restrict__ eid,
                                                    int N) {
  __shared__ int lfill[512];
  __shared__ int lrowp[512];
  int b = blockIdx.x;
  int t = threadIdx.x;
  int n0 = b << 9;
  int n1 = min(n0 + 512, N);
  int nn = n1 - n0;
  for (int i = t; i < nn; i += 256) { lfill[i] = 0; lrowp[i] = rowp[n0 + i]; }
  __syncthreads();
  int ebeg = rowp[n0], eend = rowp[n1];
  for (int i = ebeg + t; i < eend; i += 256) {
    u32 s = src_stage[i];
    u32 pk = pk_stage[i];
    int dlow = (int)(pk >> 21);
    int e = (int)(pk & 0x1FFFFFu);
    int lpos = atomicAdd(&lfill[dlow], 1);
    int pos = lrowp[dlow] + lpos;
    col[pos] = (int)s;
    eid[pos] = e;
  }
}

// ---------- weight prep: Wtb[m][n][k] = bf16(Wsrc_m[k][n]), m=0..4 ----------
__global__ void conv_weights(const float* __restrict__ conv_w,
                             const float* __restrict__ mlp_w1,
                             u32* __restrict__ Wtb) {
  int i = blockIdx.x * 256 + threadIdx.x;
  if (i >= 5 * 128 * 64) return;
  int m = i >> 13;
  int r = i & 8191;
  int n = r >> 6;
  int k2 = r & 63;
  const float* src = (m < 3) ? conv_w + (size_t)m * HD * HD
                             : mlp_w1 + (size_t)(m - 3) * HD * HD;
  float a = src[(2 * k2) * HD + n];
  float b = src[(2 * k2 + 1) * HD + n];
  Wtb[i] = pack2(a, b);
}

// ---------- node encoder: Linear(7->128) + LN + ReLU -> bf16 xb only ----------
__global__ __launch_bounds__(128) void encoder(const float* __restrict__ nf,
                                               const float* __restrict__ enc_w,
                                               const float* __restrict__ enc_b,
                                               const float* __restrict__ g,
                                               const float* __restrict__ bt,
                                               u32* __restrict__ xb, int N) {
  int n = blockIdx.x;
  int t = threadIdx.x;
  __shared__ float f[7];
  if (t < 7) f[t] = nf[(size_t)n * 7 + t];
  __syncthreads();
  float v = enc_b[t];
  #pragma unroll
  for (int k = 0; k < 7; k++) v = fmaf(f[k], enc_w[k * HD + t], v);
  float s1 = v, s2 = v * v;
  block_reduce2_128(s1, s2);
  float mu = s1 * (1.f / HD);
  float var = s2 * (1.f / HD) - mu * mu;
  float o = fmaxf((v - mu) * rsqrtf(var + LN_EPS) * g[t] + bt[t], 0.f);
  float o2 = __shfl_down(o, 1);
  if ((t & 1) == 0) xb[(size_t)n * 64 + (t >> 1)] = pack2(o, o2);
}

// ---------- MFMA GEMM: h[N,128]bf16 = xb[N,128]bf16 @ W ----------
__global__ __launch_bounds__(256) void gemm_mfma(const u32* __restrict__ xb,
                                                 const u32* __restrict__ Wt,
                                                 u32* __restrict__ h, int N) {
  __shared__ u32 lds[8192];
  int t = threadIdx.x;
  int node0 = blockIdx.x * 64;
  {
    uint4* l4 = reinterpret_cast<uint4*>(lds);
    const uint4* s4 = reinterpret_cast<const uint4*>(Wt);
    for (int i = t; i < 2048; i += 256) {
      int n = i >> 4, kc = i & 15;
      l4[(n << 4) + (kc ^ (n & 15))] = s4[i];
    }
  }
  int w = t >> 6, l = t & 63;
  int m15 = l & 15, kq = l >> 4;
  int grow = node0 + w * 16 + m15;
  bf16x8 afrag[4];
  bool rowok = grow < N;
  #pragma unroll
  for (int c = 0; c < 4; c++) {
    if (rowok)
      afrag[c] = *reinterpret_cast<const bf16x8*>(
          reinterpret_cast<const short*>(xb) + (size_t)grow * HD + c * 32 + kq * 8);
    else
      afrag[c] = bf16x8{0, 0, 0, 0, 0, 0, 0, 0};
  }
  __syncthreads();
  f32x4 acc[8];
  #pragma unroll
  for (int tl = 0; tl < 8; tl++) acc[tl] = f32x4{0.f, 0.f, 0.f, 0.f};
  const uint4* l4 = reinterpret_cast<const uint4*>(lds);
  #pragma unroll
  for (int tl = 0; tl < 8; tl++) {
    int n = tl * 16 + m15;
    #pragma unroll
    for (int c = 0; c < 4; c++) {
      bf16x8 bfrag = *reinterpret_cast<const bf16x8*>(&l4[(n << 4) + ((c * 4 + kq) ^ (n & 15))]);
      acc[tl] = __builtin_amdgcn_mfma_f32_16x16x32_bf16(afrag[c], bfrag, acc[tl], 0, 0, 0);
    }
  }
  __syncthreads();
  short* cs = reinterpret_cast<short*>(lds);
  #pragma unroll
  for (int tl = 0; tl < 8; tl++) {
    int colc = tl * 16 + m15;
    #pragma unroll
    for (int r = 0; r < 4; r++)
      cs[(w * 16 + kq * 4 + r) * 136 + colc] = (short)f2bf(acc[tl][r]);
  }
  __syncthreads();
  for (int i = t; i < 1024; i += 256) {
    int row = i >> 4;
    int node = node0 + row;
    if (node < N) {
      uint4 v = *reinterpret_cast<const uint4*>(&lds[row * 68 + (i & 15) * 4]);
      reinterpret_cast<uint4*>(h)[(size_t)node * 16 + (i & 15)] = v;
    }
  }
}

// ---------- fused gather-aggregate + bias + LN + ReLU + residual ----------
__global__ __launch_bounds__(256) void aggregate(const u32* __restrict__ h,
                                                 const int* __restrict__ row_ptr,
                                                 const int* __restrict__ col,
                                                 const float* __restrict__ dinv,
                                                 const float* __restrict__ conv_b,
                                                 const float* __restrict__ g,
                                                 const float* __restrict__ bt,
                                                 u32* __restrict__ xb,
                                                 float* __restrict__ out_x,
                                                 int N, int last) {
  int n = blockIdx.x * 4 + (threadIdx.x >> 6);
  if (n >= N) return;
  int l = threadIdx.x & 63;
  int beg = row_ptr[n], end = row_ptr[n + 1];
  float dn = dinv[n];
  u32 hv = h[(size_t)n * 64 + l];          // self loop
  float a0 = dn * bf_lo(hv), a1 = dn * bf_hi(hv);
  for (int base = beg; base < end; base += 64) {
    int m = min(64, end - base);
    int s = 0; float dv = 0.f;
    if (l < m) { s = col[base + l]; dv = dinv[s]; }
    int j = 0;
    for (; j + 8 <= m; j += 8) {
      int ss[8]; float dd[8]; u32 vv[8];
      #pragma unroll
      for (int q = 0; q < 8; q++) { ss[q] = __shfl(s, j + q); dd[q] = __shfl(dv, j + q); }
      #pragma unroll
      for (int q = 0; q < 8; q++) vv[q] = h[(size_t)ss[q] * 64 + l];
      #pragma unroll
      for (int q = 0; q < 8; q++) {
        a0 = fmaf(dd[q], bf_lo(vv[q]), a0);
        a1 = fmaf(dd[q], bf_hi(vv[q]), a1);
      }
    }
    for (; j < m; j++) {
      int sj = __shfl(s, j);
      float dj = __shfl(dv, j);
      u32 v = h[(size_t)sj * 64 + l];
      a0 = fmaf(dj, bf_lo(v), a0); a1 = fmaf(dj, bf_hi(v), a1);
    }
  }
  float2 bb = reinterpret_cast<const float2*>(conv_b)[l];
  float v0 = dn * a0 + bb.x;
  float v1 = dn * a1 + bb.y;
  float s1 = v0 + v1, s2 = v0 * v0 + v1 * v1;
  #pragma unroll
  for (int off = 32; off > 0; off >>= 1) {
    s1 += __shfl_xor(s1, off);
    s2 += __shfl_xor(s2, off);
  }
  float mu = s1 * (1.f / HD);
  float var = s2 * (1.f / HD) - mu * mu;
  float rs = rsqrtf(var + LN_EPS);
  float2 gg = reinterpret_cast<const float2*>(g)[l];
  float2 bt2 = reinterpret_cast<const float2*>(bt)[l];
  u32 xv = xb[(size_t)n * 64 + l];
  float o0 = fmaxf((v0 - mu) * rs * gg.x + bt2.x, 0.f) + bf_lo(xv);
  float o1 = fmaxf((v1 - mu) * rs * gg.y + bt2.y, 0.f) + bf_hi(xv);
  xb[(size_t)n * 64 + l] = pack2(o0, o1);
  if (last) reinterpret_cast<float2*>(out_x)[(size_t)n * 64 + l] = make_float2(o0, o1);
}

// ---------- edge scoring, dst-grouped; writes logits in CSR order ----------
__global__ __launch_bounds__(128) void edge_mlp(const u32* __restrict__ P,
                                                const u32* __restrict__ Q,
                                                const int* __restrict__ rowp,
                                                const int* __restrict__ col,
                                                const float* __restrict__ b1,
                                                const float* __restrict__ w2,
                                                const float* __restrict__ b2,
                                                float* __restrict__ tmp, int N) {
  int n = blockIdx.x * 2 + (threadIdx.x >> 6);
  if (n >= N) return;
  int l = threadIdx.x & 63;
  int g = l >> 4, li = l & 15;
  int beg = rowp[n], end = rowp[n + 1];
  if (beg == end) return;
  const uint4* P4 = reinterpret_cast<const uint4*>(P);
  uint4 qv = reinterpret_cast<const uint4*>(Q)[(size_t)n * 16 + li];
  float4 bA = reinterpret_cast<const float4*>(b1)[2 * li];
  float4 bB = reinterpret_cast<const float4*>(b1)[2 * li + 1];
  float4 wA = reinterpret_cast<const float4*>(w2)[2 * li];
  float4 wB = reinterpret_cast<const float4*>(w2)[2 * li + 1];
  float q0 = bf_lo(qv.x) + bA.x, q1 = bf_hi(qv.x) + bA.y;
  float q2 = bf_lo(qv.y) + bA.z, q3 = bf_hi(qv.y) + bA.w;
  float q4 = bf_lo(qv.z) + bB.x, q5 = bf_hi(qv.z) + bB.y;
  float q6 = bf_lo(qv.w) + bB.z, q7 = bf_hi(qv.w) + bB.w;
  float b2v = b2[0];
  for (int base = beg; base < end; base += 64) {
    int m = min(64, end - base);
    int s = 0;
    if (l < m) s = col[base + l];
    int nj = (m + 3) >> 2;
    for (int j = 0; j < nj; j++) {
      int ei = j * 4 + g;
      int sj = __shfl(s, ei);
      float acc = 0.f;
      if (ei < m) {
        uint4 pv = P4[(size_t)sj * 16 + li];
        float hh;
        hh = fmaxf(bf_lo(pv.x) + q0, 0.f); acc = fmaf(hh, wA.x, acc);
        hh = fmaxf(bf_hi(pv.x) + q1, 0.f); acc = fmaf(hh, wA.y, acc);
        hh = fmaxf(bf_lo(pv.y) + q2, 0.f); acc = fmaf(hh, wA.z, acc);
        hh = fmaxf(bf_hi(pv.y) + q3, 0.f); acc = fmaf(hh, wA.w, acc);
        hh = fmaxf(bf_lo(pv.z) + q4, 0.f); acc = fmaf(hh, wB.x, acc);
        hh = fmaxf(bf_hi(pv.z) + q5, 0.f); acc = fmaf(hh, wB.y, acc);
        hh = fmaxf(bf_lo(pv.w) + q6, 0.f); acc = fmaf(hh, wB.z, acc);
        hh = fmaxf(bf_hi(pv.w) + q7, 0.f); acc = fmaf(hh, wB.w, acc);
      }
      acc += __shfl_down(acc, 8, 16);
      acc += __shfl_down(acc, 4, 16);
      acc += __shfl_down(acc, 2, 16);
      acc += __shfl_down(acc, 1, 16);
      if (li == 0 && ei < m) tmp[base + ei] = acc + b2v;
    }
  }
}

// ---------- windowed permute-scatter: out[eid[i]] = tmp[i] ----------
__global__ void permute_scatter(const float* __restrict__ tmp, const int* __restrict__ eid,
                                float* __restrict__ out, int E) {
  int cls = blockIdx.x & 7;
  if (cls > 6) return;                  // E=1.6M -> e>>18 in [0,6]
  int nb = gridDim.x >> 3;
  int bid = blockIdx.x >> 3;
  for (int i = bid * 256 + threadIdx.x; i < E; i += nb * 256) {
    int e = eid[i];
    if ((e >> 18) == cls) out[e] = tmp[i];
  }
}

extern "C" void kernel_launch(void* const* d_in, const int* in_sizes, int n_in,
                              void* d_out, int out_size, void* d_ws, size_t ws_size,
                              hipStream_t stream) {
  const float* node_features = (const float*)d_in[0];
  const int*   edge_index    = (const int*)d_in[1];
  const float* enc_w    = (const float*)d_in[3];
  const float* enc_b    = (const float*)d_in[4];
  const float* enc_ln_g = (const float*)d_in[5];
  const float* enc_ln_b = (const float*)d_in[6];
  const float* conv_w   = (const float*)d_in[7];
  const float* conv_b   = (const float*)d_in[8];
  const float* ln_g     = (const float*)d_in[9];
  const float* ln_b     = (const float*)d_in[10];
  const float* mlp_w1   = (const float*)d_in[11];
  const float* mlp_b1   = (const float*)d_in[12];
  const float* mlp_w2   = (const float*)d_in[13];
  const float* mlp_b2   = (const float*)d_in[14];

  const int N = in_sizes[0] / 7;
  const int E = in_sizes[1] / 2;
  const int* src = edge_index;
  const int* dst = edge_index + E;
  const int nbk = (N + 511) >> 9;        // dst buckets of 512 nodes

  char* ws = (char*)d_ws;
  u32*   h    = (u32*)ws;    ws += (size_t)N * 64 * 4;
  u32*   qb   = (u32*)ws;    ws += (size_t)N * 64 * 4;
  u32*   xb   = (u32*)ws;    ws += (size_t)N * 64 * 4;
  u32*   Wtb  = (u32*)ws;    ws += (size_t)5 * 128 * 64 * 4;
  float* dinv = (float*)ws;  ws += (size_t)N * 4;
  int* counts = (int*)ws;    ws += (size_t)N * 4;
  int* bfill  = (int*)ws;    ws += 1024;
  int* col    = (int*)ws;    ws += (size_t)E * 4;
  int* eid    = (int*)ws;    ws += (size_t)E * 4;
  u32* src_st = (u32*)ws;    ws += (size_t)E * 4;
  u32* pk_st  = (u32*)ws;    ws += (size_t)E * 4;
  int* rowp   = (int*)ws;    ws += (size_t)(N + 1) * 4;
  int* bsums  = (int*)ws;    ws += 4096;
  float* tmp  = (float*)ws;  ws += (size_t)E * 4;

  float* out_x      = (float*)d_out;
  float* out_logits = out_x + (size_t)N * HD;

  const int T = 256;
  int nblk = (N + 1023) / 1024;

  // degrees -> rowp
  init_counts<<<(N + T - 1) / T, T, 0, stream>>>(counts, N);
  count_deg<<<(E + T - 1) / T, T, 0, stream>>>(dst, counts, E);
  scan1<<<nblk, 1024, 0, stream>>>(counts, rowp, bsums, N);
  scan2<<<1, 1024, 0, stream>>>(bsums, nblk);
  scan3<<<(N + T - 1) / T, T, 0, stream>>>(rowp, bsums, N);
  compute_dinv<<<(N + T - 1) / T, T, 0, stream>>>(counts, dinv, N);

  // two-pass CSR build (coalesced staging, then per-bucket LDS scatter)
  init_bfill<<<(nbk + 255) / 256, 256, 0, stream>>>(rowp, bfill, nbk);
  binscat<<<(E + 8191) / 8192, 256, 0, stream>>>(src, dst, bfill, src_st, pk_st, E, nbk);
  bucket_build<<<nbk, 256, 0, stream>>>(src_st, pk_st, rowp, col, eid, N);

  conv_weights<<<(5 * 128 * 64 + T - 1) / T, T, 0, stream>>>(conv_w, mlp_w1, Wtb);

  encoder<<<N, 128, 0, stream>>>(node_features, enc_w, enc_b, enc_ln_g, enc_ln_b, xb, N);

  int gblk = (N + 63) / 64;
  int ablk = (N + 3) / 4;
  for (int l = 0; l < 3; l++) {
    gemm_mfma<<<gblk, 256, 0, stream>>>(xb, Wtb + (size_t)l * 8192, h, N);
    aggregate<<<ablk, 256, 0, stream>>>(h, rowp, col, dinv,
                                        conv_b + l * HD, ln_g + l * HD, ln_b + l * HD,
                                        xb, out_x, N, l == 2 ? 1 : 0);
  }

  gemm_mfma<<<gblk, 256, 0, stream>>>(xb, Wtb + (size_t)3 * 8192, h, N);   // P
  gemm_mfma<<<gblk, 256, 0, stream>>>(xb, Wtb + (size_t)4 * 8192, qb, N);  // Q
  edge_mlp<<<(N + 1) / 2, 128, 0, stream>>>(h, qb, rowp, col, mlp_b1, mlp_w2, mlp_b2, tmp, N);
  permute_scatter<<<3584, 256, 0, stream>>>(tmp, eid, out_logits, E);
}